// Round 1
// baseline (336.836 us; speedup 1.0000x reference)
//
#include <hip/hip_runtime.h>
#include <hip/hip_bf16.h>
#include <stdint.h>

#define B_    8
#define N_    2048
#define DIN_  256
#define DOUT_ 256
#define ALPHA_ 0.2f
#define EPS_   1e-6f

typedef __attribute__((ext_vector_type(8))) short  short8;
typedef __attribute__((ext_vector_type(4))) float  float4v;

static __device__ __forceinline__ unsigned short f2bf(float x) {
    union { float f; unsigned int u; } c; c.f = x;
    unsigned int r = (c.u + 0x7fffu + ((c.u >> 16) & 1u)) >> 16;
    return (unsigned short)r;
}

// ---------------- K1: Wh = h @ W (fp32), also writes WhT bf16 [b][f][j] ----
__global__ __launch_bounds__(256) void k_wh(const float* __restrict__ h,
                                            const float* __restrict__ W,
                                            float* __restrict__ Wh,
                                            unsigned short* __restrict__ WhT) {
    __shared__ __align__(16) float hs[32][256];
    const int t   = threadIdx.x;
    const int blk = blockIdx.x;        // 512 blocks, 32 rows each
    const int r0  = blk * 32;          // flat row (b*2048 + i)

    // stage 32x256 h tile, coalesced float4
    const float4v* hg  = (const float4v*)(h + (size_t)r0 * 256);
    float4v*       hsv = (float4v*)&hs[0][0];
#pragma unroll
    for (int k = 0; k < 8; ++k) hsv[t + 256 * k] = hg[t + 256 * k];
    __syncthreads();

    float acc[32];
#pragma unroll
    for (int r = 0; r < 32; ++r) acc[r] = 0.f;

    const int f = t;                   // each thread owns one output column
    for (int d0 = 0; d0 < 256; d0 += 4) {
        const float w0 = W[(d0 + 0) * 256 + f];
        const float w1 = W[(d0 + 1) * 256 + f];
        const float w2 = W[(d0 + 2) * 256 + f];
        const float w3 = W[(d0 + 3) * 256 + f];
#pragma unroll
        for (int r = 0; r < 32; ++r) {
            float4v hv = *(const float4v*)&hs[r][d0];   // broadcast b128
            acc[r] = fmaf(hv.x, w0, fmaf(hv.y, w1, fmaf(hv.z, w2, fmaf(hv.w, w3, acc[r]))));
        }
    }

    // Wh fp32, coalesced over f
#pragma unroll
    for (int r = 0; r < 32; ++r) Wh[(size_t)(r0 + r) * 256 + f] = acc[r];

    // WhT bf16 [b][f][j]: thread writes 32 consecutive j as 4x16B
    const int b  = r0 >> 11;
    const int j0 = r0 & 2047;
    unsigned short* wt = WhT + ((size_t)(b * 256 + f) * 2048 + j0);
#pragma unroll
    for (int q = 0; q < 4; ++q) {
        uint4 v;
        v.x = (unsigned int)f2bf(acc[q * 8 + 0]) | ((unsigned int)f2bf(acc[q * 8 + 1]) << 16);
        v.y = (unsigned int)f2bf(acc[q * 8 + 2]) | ((unsigned int)f2bf(acc[q * 8 + 3]) << 16);
        v.z = (unsigned int)f2bf(acc[q * 8 + 4]) | ((unsigned int)f2bf(acc[q * 8 + 5]) << 16);
        v.w = (unsigned int)f2bf(acc[q * 8 + 6]) | ((unsigned int)f2bf(acc[q * 8 + 7]) << 16);
        *(uint4*)(wt + q * 8) = v;
    }
}

// ---------------- K2: s1 = Wh@a1, s2 = Wh@a2 (wave per row) ----------------
__global__ __launch_bounds__(256) void k_s(const float* __restrict__ Wh,
                                           const float* __restrict__ a,
                                           float* __restrict__ s1,
                                           float* __restrict__ s2) {
    const int t    = threadIdx.x;
    const int lane = t & 63;
    const int w    = t >> 6;
    const int row  = blockIdx.x * 4 + w;   // 4096 blocks

    float4v wv = *(const float4v*)&Wh[(size_t)row * 256 + lane * 4];
    float4v a1 = *(const float4v*)&a[lane * 4];
    float4v a2 = *(const float4v*)&a[256 + lane * 4];
    float v1 = wv.x * a1.x + wv.y * a1.y + wv.z * a1.z + wv.w * a1.w;
    float v2 = wv.x * a2.x + wv.y * a2.y + wv.z * a2.z + wv.w * a2.w;
#pragma unroll
    for (int off = 32; off; off >>= 1) {
        v1 += __shfl_xor(v1, off);
        v2 += __shfl_xor(v2, off);
    }
    if (lane == 0) { s1[row] = v1; s2[row] = v2; }
}

// ---------------- K3: fused softmax-weighted aggregation -------------------
// block: 256 thr (4 waves), 32 i-rows x 256 f. K-loop over j in steps of 32.
__global__ __launch_bounds__(256) void k_attn(const float* __restrict__ adj,
                                              const unsigned short* __restrict__ WhT,
                                              const float* __restrict__ s1g,
                                              const float* __restrict__ s2g,
                                              float* __restrict__ out) {
    __shared__ __align__(16) unsigned short p_lds[32][40];  // pad 32->40: 80B stride
    __shared__ float rsum_lds[32];

    const int t    = threadIdx.x;
    const int lane = t & 63;
    const int wv   = t >> 6;            // wave 0..3 -> f block of 64
    const int blk  = blockIdx.x;        // 512
    const int b    = blk >> 6;
    const int i0   = (blk & 63) * 32;

    // p-compute assignment: thread -> (i row, 4 consecutive j)
    const int ip = t >> 3;              // 0..31
    const int jq = t & 7;               // 0..7  -> j0 = jq*4
    const float* adjp = adj + (size_t)(b * 2048 + i0 + ip) * 2048 + jq * 4;
    const float  s1v  = s1g[b * 2048 + i0 + ip];
    const float* s2p  = s2g + b * 2048 + jq * 4;

    // B-fragment addressing: lane -> (f, j-chunk)
    const int m    = lane & 15;
    const int quad = lane >> 4;
    const size_t bbase = (size_t)(b * 256 + wv * 64 + m) * 2048 + quad * 8;

    float4v acc[2][4];
#pragma unroll
    for (int it = 0; it < 2; ++it)
#pragma unroll
        for (int ft = 0; ft < 4; ++ft)
#pragma unroll
            for (int r = 0; r < 4; ++r) acc[it][ft][r] = 0.f;

    // prologue: step-0 operands
    float4v adjv = *(const float4v*)adjp;
    float4v s2v  = *(const float4v*)s2p;
    short8  bfr[4];
#pragma unroll
    for (int ft = 0; ft < 4; ++ft)
        bfr[ft] = *(const short8*)(WhT + bbase + (size_t)ft * 16 * 2048);

    float rsum = 0.f;

    for (int step = 0; step < 64; ++step) {
        const int nxt = (step + 1 < 64) ? step + 1 : 0;   // last-iter loads harmless

        // ---- compute p for 4 j's (fp32), accumulate rowsum, pack bf16 ----
        float e0 = s1v + s2v.x, e1 = s1v + s2v.y, e2 = s1v + s2v.z, e3 = s1v + s2v.w;
        e0 = fmaxf(e0, ALPHA_ * e0); e1 = fmaxf(e1, ALPHA_ * e1);
        e2 = fmaxf(e2, ALPHA_ * e2); e3 = fmaxf(e3, ALPHA_ * e3);
        float p0 = (adjv.x + EPS_) * __expf(e0);
        float p1 = (adjv.y + EPS_) * __expf(e1);
        float p2 = (adjv.z + EPS_) * __expf(e2);
        float p3 = (adjv.w + EPS_) * __expf(e3);
        rsum += (p0 + p1) + (p2 + p3);
        {
            uint2 v;
            v.x = (unsigned int)f2bf(p0) | ((unsigned int)f2bf(p1) << 16);
            v.y = (unsigned int)f2bf(p2) | ((unsigned int)f2bf(p3) << 16);
            *(uint2*)&p_lds[ip][jq * 4] = v;
        }

        // prefetch next-step adj/s2 (registers)
        const float4v adj_n = *(const float4v*)(adjp + (size_t)nxt * 32);
        const float4v s2_n  = *(const float4v*)(s2p + nxt * 32);

        __syncthreads();   // p_lds visible

        // prefetch next-step B-fragments from L2-resident WhT
        short8 bn[4];
#pragma unroll
        for (int ft = 0; ft < 4; ++ft)
            bn[ft] = *(const short8*)(WhT + bbase + (size_t)ft * 16 * 2048 + (size_t)nxt * 32);

        // A-fragments from LDS (b128, padded stride), then 8 MFMAs
        short8 af0 = *(const short8*)&p_lds[m][quad * 8];
        short8 af1 = *(const short8*)&p_lds[16 + m][quad * 8];
#pragma unroll
        for (int ft = 0; ft < 4; ++ft) {
            acc[0][ft] = __builtin_amdgcn_mfma_f32_16x16x32_bf16(af0, bfr[ft], acc[0][ft], 0, 0, 0);
            acc[1][ft] = __builtin_amdgcn_mfma_f32_16x16x32_bf16(af1, bfr[ft], acc[1][ft], 0, 0, 0);
        }

        __syncthreads();   // A-frag reads done before next p-writes

        adjv = adj_n; s2v = s2_n;
#pragma unroll
        for (int ft = 0; ft < 4; ++ft) bfr[ft] = bn[ft];
    }

    // rowsum: reduce over jq (lanes xor 1,2,4 share same i)
    float r = rsum;
    r += __shfl_xor(r, 1); r += __shfl_xor(r, 2); r += __shfl_xor(r, 4);
    if ((t & 7) == 0) rsum_lds[ip] = r;
    __syncthreads();

    // epilogue: divide + store. C/D layout: col = lane&15, row = (lane>>4)*4 + reg
#pragma unroll
    for (int it = 0; it < 2; ++it) {
#pragma unroll
        for (int reg = 0; reg < 4; ++reg) {
            const int row = it * 16 + quad * 4 + reg;
            const float inv = 1.0f / rsum_lds[row];
#pragma unroll
            for (int ft = 0; ft < 4; ++ft) {
                out[(size_t)(b * 2048 + i0 + row) * 256 + wv * 64 + ft * 16 + m] =
                    acc[it][ft][reg] * inv;
            }
        }
    }
}

extern "C" void kernel_launch(void* const* d_in, const int* in_sizes, int n_in,
                              void* d_out, int out_size, void* d_ws, size_t ws_size,
                              hipStream_t stream) {
    const float* h   = (const float*)d_in[0];   // (8,2048,256)
    const float* adj = (const float*)d_in[1];   // (8,2048,2048)
    const float* W   = (const float*)d_in[2];   // (256,256)
    const float* a   = (const float*)d_in[3];   // (512,1)
    float* out = (float*)d_out;                 // (8,2048,256)

    // workspace layout
    float*          Wh  = (float*)d_ws;                                    // 16.8 MB
    unsigned short* WhT = (unsigned short*)((char*)d_ws + 16777216);       // 8.4 MB
    float*          s1  = (float*)((char*)d_ws + 16777216 + 8388608);      // 64 KB
    float*          s2  = s1 + 16384;                                      // 64 KB

    k_wh<<<dim3(512), dim3(256), 0, stream>>>(h, W, Wh, WhT);
    k_s<<<dim3(4096), dim3(256), 0, stream>>>(Wh, a, s1, s2);
    k_attn<<<dim3(512), dim3(256), 0, stream>>>(adj, WhT, s1, s2, out);
}

// Round 2
// 260.602 us; speedup vs baseline: 1.2925x; 1.2925x over previous
//
#include <hip/hip_runtime.h>
#include <hip/hip_bf16.h>
#include <stdint.h>

#define ALPHA_ 0.2f
#define EPS_   1e-6f

typedef __attribute__((ext_vector_type(8))) short  short8;
typedef __attribute__((ext_vector_type(4))) float  float4v;

static __device__ __forceinline__ unsigned short f2bf(float x) {
    union { float f; unsigned int u; } c; c.f = x;
    return (unsigned short)((c.u + 0x7fffu + ((c.u >> 16) & 1u)) >> 16);
}

// barrier that does NOT drain vmcnt: LDS visibility only (own ds ops retire via
// lgkmcnt(0); s_barrier orders waves). Global prefetches stay in flight.
#define LGKM_BARRIER() asm volatile("s_waitcnt lgkmcnt(0)\n\ts_barrier" ::: "memory")

// ---------------- K0: WT[f][d] = bf16(W[d][f]) ------------------------------
__global__ __launch_bounds__(256) void k_wt(const float* __restrict__ W,
                                            unsigned short* __restrict__ WT) {
    const int t  = threadIdx.x;
    const int f  = blockIdx.x * 8 + (t >> 5);
    const int d0 = (t & 31) * 8;
    unsigned short v[8];
#pragma unroll
    for (int k = 0; k < 8; ++k) v[k] = f2bf(W[(d0 + k) * 256 + f]);
    uint4 o;
    o.x = (unsigned)v[0] | ((unsigned)v[1] << 16);
    o.y = (unsigned)v[2] | ((unsigned)v[3] << 16);
    o.z = (unsigned)v[4] | ((unsigned)v[5] << 16);
    o.w = (unsigned)v[6] | ((unsigned)v[7] << 16);
    *(uint4*)(WT + f * 256 + d0) = o;
}

// ---------------- K1: MFMA Wh = h@W (bf16 in, fp32 acc); fused s1/s2 --------
__global__ __launch_bounds__(256) void k_wh(const float* __restrict__ h,
                                            const unsigned short* __restrict__ WT,
                                            const float* __restrict__ a,
                                            unsigned short* __restrict__ WhT,
                                            float* __restrict__ s1g,
                                            float* __restrict__ s2g) {
    __shared__ __align__(16) unsigned short A_lds[32][264];  // pad 256->264
    __shared__ float s1p[32], s2p[32];
    const int t    = threadIdx.x;
    const int lane = t & 63;
    const int wv   = t >> 6;
    const int m    = lane & 15;
    const int quad = lane >> 4;
    const int r0   = blockIdx.x * 32;     // 512 blocks
    const int b    = r0 >> 11;
    const int j0   = r0 & 2047;

    if (t < 32) { s1p[t] = 0.f; s2p[t] = 0.f; }

    // stage h tile fp32 -> bf16 LDS (A layout [row][d], coalesced float4)
#pragma unroll
    for (int k = 0; k < 8; ++k) {
        const int flat = t + k * 256;
        const int r  = flat >> 6;
        const int d4 = flat & 63;
        float4v hv = *(const float4v*)(h + (size_t)(r0 + r) * 256 + d4 * 4);
        uint2 pk;
        pk.x = (unsigned)f2bf(hv.x) | ((unsigned)f2bf(hv.y) << 16);
        pk.y = (unsigned)f2bf(hv.z) | ((unsigned)f2bf(hv.w) << 16);
        *(uint2*)&A_lds[r][d4 * 4] = pk;
    }
    __syncthreads();

    const int fbase = wv * 64;
    float4v acc[2][4];
#pragma unroll
    for (int it = 0; it < 2; ++it)
#pragma unroll
        for (int ft = 0; ft < 4; ++ft)
#pragma unroll
            for (int r = 0; r < 4; ++r) acc[it][ft][r] = 0.f;

    const unsigned short* wtp = WT + (size_t)(fbase + m) * 256 + quad * 8;
    short8 bcur[4], bnxt[4];
#pragma unroll
    for (int ft = 0; ft < 4; ++ft) bcur[ft] = *(const short8*)(wtp + ft * 16 * 256);

#pragma unroll
    for (int kc = 0; kc < 8; ++kc) {
        const int kn = (kc + 1) & 7;
#pragma unroll
        for (int ft = 0; ft < 4; ++ft)
            bnxt[ft] = *(const short8*)(wtp + ft * 16 * 256 + kn * 32);
        short8 af0 = *(const short8*)&A_lds[m][kc * 32 + quad * 8];
        short8 af1 = *(const short8*)&A_lds[16 + m][kc * 32 + quad * 8];
#pragma unroll
        for (int ft = 0; ft < 4; ++ft) {
            acc[0][ft] = __builtin_amdgcn_mfma_f32_16x16x32_bf16(af0, bcur[ft], acc[0][ft], 0, 0, 0);
            acc[1][ft] = __builtin_amdgcn_mfma_f32_16x16x32_bf16(af1, bcur[ft], acc[1][ft], 0, 0, 0);
        }
#pragma unroll
        for (int ft = 0; ft < 4; ++ft) bcur[ft] = bnxt[ft];
    }

    // fused s1/s2: per-lane partial over its f columns, reduce over m, LDS atomics
    float a1v[4], a2v[4];
#pragma unroll
    for (int ft = 0; ft < 4; ++ft) {
        a1v[ft] = a[fbase + ft * 16 + m];
        a2v[ft] = a[256 + fbase + ft * 16 + m];
    }
#pragma unroll
    for (int it = 0; it < 2; ++it) {
#pragma unroll
        for (int reg = 0; reg < 4; ++reg) {
            float v1 = 0.f, v2 = 0.f;
#pragma unroll
            for (int ft = 0; ft < 4; ++ft) {
                const float c = acc[it][ft][reg];
                v1 = fmaf(c, a1v[ft], v1);
                v2 = fmaf(c, a2v[ft], v2);
            }
            v1 += __shfl_xor(v1, 1); v2 += __shfl_xor(v2, 1);
            v1 += __shfl_xor(v1, 2); v2 += __shfl_xor(v2, 2);
            v1 += __shfl_xor(v1, 4); v2 += __shfl_xor(v2, 4);
            v1 += __shfl_xor(v1, 8); v2 += __shfl_xor(v2, 8);
            if (m == 0) {
                const int row = it * 16 + quad * 4 + reg;
                atomicAdd(&s1p[row], v1);
                atomicAdd(&s2p[row], v2);
            }
        }
    }

    // WhT bf16 [b][f][j]
    unsigned short* wto = WhT + (size_t)(b * 256 + fbase) * 2048 + j0;
#pragma unroll
    for (int it = 0; it < 2; ++it)
#pragma unroll
        for (int ft = 0; ft < 4; ++ft)
#pragma unroll
            for (int reg = 0; reg < 4; ++reg)
                wto[(size_t)(ft * 16 + m) * 2048 + it * 16 + quad * 4 + reg] =
                    f2bf(acc[it][ft][reg]);

    __syncthreads();
    if (t < 32) {
        s1g[(size_t)b * 2048 + j0 + t] = s1p[t];
        s2g[(size_t)b * 2048 + j0 + t] = s2p[t];
    }
}

// ---------------- K3: fused softmax-weighted aggregation --------------------
// 512 blocks, 256 thr. 32 i x 256 f per block; j in 16 steps of 128.
// Double-buffered p tile, ONE lgkm-only barrier per step; adj prefetched one
// full step ahead (stays in flight across the barrier).
__global__ __launch_bounds__(256, 2) void k_attn(const float* __restrict__ adj,
                                                 const unsigned short* __restrict__ WhT,
                                                 const float* __restrict__ s1g,
                                                 const float* __restrict__ s2g,
                                                 float* __restrict__ out) {
    __shared__ __align__(16) unsigned short pbuf[2][32][136];  // pad 128->136
    __shared__ __align__(16) float s2_lds[2048];
    __shared__ float rsum_lds[32];

    const int t    = threadIdx.x;
    const int lane = t & 63;
    const int wv   = t >> 6;
    const int m    = lane & 15;
    const int quad = lane >> 4;
    const int blk  = blockIdx.x;        // 512
    const int b    = blk >> 6;
    const int i0   = (blk & 63) * 32;

    const int ip = t >> 3;              // 0..31 (row)
    const int jq = t & 7;               // 0..7

    // stage s2 row (8 KB) once
    {
        const float4v* sg = (const float4v*)(s2g + (size_t)b * 2048);
        float4v v0 = sg[t], v1 = sg[t + 256];
        ((float4v*)s2_lds)[t]       = v0;
        ((float4v*)s2_lds)[t + 256] = v1;
    }
    const float s1v = s1g[(size_t)b * 2048 + i0 + ip];
    const float* adjp = adj + (size_t)(b * 2048 + i0 + ip) * 2048 + jq * 4;

    float4v adjv[2][4];
#pragma unroll
    for (int c = 0; c < 4; ++c) adjv[0][c] = *(const float4v*)(adjp + c * 32);

    const size_t bbase = (size_t)(b * 256 + wv * 64 + m) * 2048 + quad * 8;

    float4v acc[2][4];
#pragma unroll
    for (int it = 0; it < 2; ++it)
#pragma unroll
        for (int ft = 0; ft < 4; ++ft)
#pragma unroll
            for (int r = 0; r < 4; ++r) acc[it][ft][r] = 0.f;

    float rsum = 0.f;
    __syncthreads();   // s2_lds visible (one-time full barrier)

#pragma unroll
    for (int step = 0; step < 16; ++step) {
        const int cur   = step & 1, nx = cur ^ 1;
        const int nstep = (step + 1) & 15;   // last-iter wraps: harmless reload

        // ---- p for 16 j (4 groups of 4), fp32, pack bf16 into pbuf[cur] ----
#pragma unroll
        for (int c = 0; c < 4; ++c) {
            const float4v av  = adjv[cur][c];
            const float4v s2v = *(const float4v*)&s2_lds[step * 128 + jq * 4 + c * 32];
            float e0 = s1v + s2v.x, e1 = s1v + s2v.y, e2 = s1v + s2v.z, e3 = s1v + s2v.w;
            e0 = fmaxf(e0, ALPHA_ * e0); e1 = fmaxf(e1, ALPHA_ * e1);
            e2 = fmaxf(e2, ALPHA_ * e2); e3 = fmaxf(e3, ALPHA_ * e3);
            const float p0 = (av.x + EPS_) * __expf(e0);
            const float p1 = (av.y + EPS_) * __expf(e1);
            const float p2 = (av.z + EPS_) * __expf(e2);
            const float p3 = (av.w + EPS_) * __expf(e3);
            rsum += (p0 + p1) + (p2 + p3);
            uint2 pk;
            pk.x = (unsigned)f2bf(p0) | ((unsigned)f2bf(p1) << 16);
            pk.y = (unsigned)f2bf(p2) | ((unsigned)f2bf(p3) << 16);
            *(uint2*)&pbuf[cur][ip][jq * 4 + c * 32] = pk;
        }

        // prefetch next-step adj (global, survives the lgkm barrier)
#pragma unroll
        for (int c = 0; c < 4; ++c)
            adjv[nx][c] = *(const float4v*)(adjp + (size_t)nstep * 128 + c * 32);

        LGKM_BARRIER();

        // ---- MFMA phase: B frags streamed from L2-resident WhT ----
#pragma unroll
        for (int kc = 0; kc < 4; ++kc) {
            short8 bf[4];
#pragma unroll
            for (int ft = 0; ft < 4; ++ft)
                bf[ft] = *(const short8*)(WhT + bbase + (size_t)ft * 16 * 2048
                                          + step * 128 + kc * 32);
            short8 af0 = *(const short8*)&pbuf[cur][m][kc * 32 + quad * 8];
            short8 af1 = *(const short8*)&pbuf[cur][16 + m][kc * 32 + quad * 8];
#pragma unroll
            for (int ft = 0; ft < 4; ++ft) {
                acc[0][ft] = __builtin_amdgcn_mfma_f32_16x16x32_bf16(af0, bf[ft], acc[0][ft], 0, 0, 0);
                acc[1][ft] = __builtin_amdgcn_mfma_f32_16x16x32_bf16(af1, bf[ft], acc[1][ft], 0, 0, 0);
            }
        }
    }

    // rowsum reduce over jq (lanes xor 1,2,4 share ip)
    float r = rsum;
    r += __shfl_xor(r, 1); r += __shfl_xor(r, 2); r += __shfl_xor(r, 4);
    if (jq == 0) rsum_lds[ip] = r;
    __syncthreads();

    // epilogue: C/D layout col=lane&15, row=quad*4+reg (+16 per i-tile)
#pragma unroll
    for (int it = 0; it < 2; ++it) {
#pragma unroll
        for (int reg = 0; reg < 4; ++reg) {
            const int row = it * 16 + quad * 4 + reg;
            const float inv = 1.0f / rsum_lds[row];
#pragma unroll
            for (int ft = 0; ft < 4; ++ft) {
                out[(size_t)(b * 2048 + i0 + row) * 256 + wv * 64 + ft * 16 + m] =
                    acc[it][ft][reg] * inv;
            }
        }
    }
}

extern "C" void kernel_launch(void* const* d_in, const int* in_sizes, int n_in,
                              void* d_out, int out_size, void* d_ws, size_t ws_size,
                              hipStream_t stream) {
    const float* h   = (const float*)d_in[0];   // (8,2048,256)
    const float* adj = (const float*)d_in[1];   // (8,2048,2048)
    const float* W   = (const float*)d_in[2];   // (256,256)
    const float* a   = (const float*)d_in[3];   // (512,1)
    float* out = (float*)d_out;                 // (8,2048,256)

    unsigned short* WhT = (unsigned short*)d_ws;                        // 8.4 MB
    unsigned short* WT  = (unsigned short*)((char*)d_ws + 8388608);     // 128 KB
    float*          s1  = (float*)((char*)d_ws + 8388608 + 131072);     // 64 KB
    float*          s2  = s1 + 16384;                                   // 64 KB

    k_wt  <<<dim3(32),  dim3(256), 0, stream>>>(W, WT);
    k_wh  <<<dim3(512), dim3(256), 0, stream>>>(h, WT, a, WhT, s1, s2);
    k_attn<<<dim3(512), dim3(256), 0, stream>>>(adj, WhT, s1, s2, out);
}